// Round 14
// baseline (210.173 us; speedup 1.0000x reference)
//
#include <hip/hip_runtime.h>
#include <hip/hip_bf16.h>

#define NPTS  1048576
#define GRID  1024
#define NTILE 16384  // NPTS / 64
#define C2    2.8853900817779268f   // 2*log2(e)

typedef __attribute__((ext_vector_type(8))) short  s16x8;
typedef __attribute__((ext_vector_type(4))) float  f32x4;

__device__ __forceinline__ unsigned short bf16r(float v) {
  unsigned u = __builtin_bit_cast(unsigned, v);
  return (unsigned short)((u + 0x7fffu + ((u >> 16) & 1u)) >> 16);
}
__device__ __forceinline__ unsigned pack_bf16x2(float lo, float hi) {
  __hip_bfloat162 h = __float22bfloat162_rn(float2{lo, hi});
  unsigned r;
  __builtin_memcpy(&r, &h, sizeof(r));
  return r;
}
// tanh(s) with bias pre-folded: bc = bias*C2  (trans ops are ~full-rate on gfx950)
__device__ __forceinline__ float tanh_e(float acc, float bc) {
  float e = __builtin_amdgcn_exp2f(fmaf(acc, C2, bc));
  return 1.0f - 2.0f * __builtin_amdgcn_rcpf(1.0f + e);
}
__device__ __forceinline__ float sigm_fast(float x) {
  return __builtin_amdgcn_rcpf(1.0f + __builtin_amdgcn_exp2f(x * -1.4426950408889634f));
}

// ws layout (u16 units) — W stored TRANSPOSED as MFMA A-fragments (natural n order):
//  [0 .. 49152)     : ws[((l*8 + nbg)*4 + kt)*512 + lane*8 + e] =
//                     bf16( W_{l+2}[k*128 + n] ), k = kt*32 + (lane>>4)*8 + e,
//                     n = nbg*16 + (lane&15);  l=0..2 (W2,W3,W4)
//  [49152 .. 51200) : W5 A-frag image: ws[49152 + kt*512 + lane*8 + e] =
//                     (lane&15)<2 ? bf16(W5[k*2 + (lane&15)]) : 0
__global__ void prep_kernel(const float* __restrict__ W2, const float* __restrict__ W3,
                            const float* __restrict__ W4, const float* __restrict__ W5,
                            unsigned short* __restrict__ ws)
{
  int tid = blockIdx.x * 256 + threadIdx.x;
  if (tid < 49152) {
    int l    = tid >> 14;
    int idx  = tid & 16383;
    int e    = idx & 7;
    int lane = (idx >> 3) & 63;
    int kt   = (idx >> 9) & 3;
    int nbg  = (idx >> 11) & 7;
    int k = kt * 32 + (lane >> 4) * 8 + e;
    int n = nbg * 16 + (lane & 15);
    const float* W = (l == 0) ? W2 : (l == 1) ? W3 : W4;
    ws[tid] = bf16r(W[k * 128 + n]);
  } else if (tid < 51200) {
    int idx  = tid - 49152;
    int e    = idx & 7;
    int lane = (idx >> 3) & 63;
    int kt   = idx >> 9;
    int k  = kt * 32 + (lane >> 4) * 8 + e;
    int nl = lane & 15;
    ws[tid] = (nl < 2) ? bf16r(W5[k * 2 + nl]) : (unsigned short)0;
  }
}

// one hidden layer: D = W^T·h^T, tanh, write back. WA bound statically via inlining.
__device__ __forceinline__ void layer_fwd(const s16x8 WA[2][4],
                                          const unsigned char* bufR, unsigned char* bufW,
                                          const float* bctab_l,
                                          unsigned rBase, unsigned wBase0, unsigned wBase1,
                                          int wid, int lg)
{
  const f32x4 bcl0 = *(const f32x4*)(bctab_l + wid * 32 + lg * 4);
  const f32x4 bcl1 = *(const f32x4*)(bctab_l + wid * 32 + 16 + lg * 4);
#pragma unroll
  for (int mt = 0; mt < 4; ++mt) {
    s16x8 B[4];
#pragma unroll
    for (int kt = 0; kt < 4; ++kt)
      B[kt] = *(const s16x8*)(bufR + rBase + mt * 4096 + kt * 1024);
    f32x4 acc0 = f32x4{0.f, 0.f, 0.f, 0.f};
    f32x4 acc1 = f32x4{0.f, 0.f, 0.f, 0.f};
#pragma unroll
    for (int kt = 0; kt < 4; ++kt) {
      acc0 = __builtin_amdgcn_mfma_f32_16x16x32_bf16(WA[0][kt], B[kt], acc0, 0, 0, 0);
      acc1 = __builtin_amdgcn_mfma_f32_16x16x32_bf16(WA[1][kt], B[kt], acc1, 0, 0, 0);
    }
    {
      float t0 = tanh_e(acc0[0], bcl0[0]);
      float t1 = tanh_e(acc0[1], bcl0[1]);
      float t2 = tanh_e(acc0[2], bcl0[2]);
      float t3 = tanh_e(acc0[3], bcl0[3]);
      *(uint2*)(bufW + wBase0 + mt * 4096) = uint2{pack_bf16x2(t0, t1), pack_bf16x2(t2, t3)};
    }
    {
      float t0 = tanh_e(acc1[0], bcl1[0]);
      float t1 = tanh_e(acc1[1], bcl1[1]);
      float t2 = tanh_e(acc1[2], bcl1[2]);
      float t3 = tanh_e(acc1[3], bcl1[3]);
      *(uint2*)(bufW + wBase1 + mt * 4096) = uint2{pack_bf16x2(t0, t1), pack_bf16x2(t2, t3)};
    }
  }
}

__global__ __launch_bounds__(256, 4)
void mlp_kernel(const float* __restrict__ xy, const float* __restrict__ Uin,
                const float* __restrict__ W1, const float* __restrict__ b1,
                const float* __restrict__ b2, const float* __restrict__ b3,
                const float* __restrict__ b4, const float* __restrict__ b5,
                const unsigned short* __restrict__ ws, float* __restrict__ out)
{
  // ping-pong h buffers, FRAGMENT-MAJOR, 64-point tile (mt=0..3):
  //   hbuf[(mt*4+kt)*1024 + lane*16 + e*2] = h[mt*16+(lane&15)][kt*32+(lane>>4)*8+e]
  __shared__ __align__(16) unsigned char hbuf0[16384];
  __shared__ __align__(16) unsigned char hbuf1[16384];
  __shared__ __align__(16) float         w1tab[384];   // w1x[128],w1y[128],b1[128]
  __shared__ __align__(16) float         bctab[384];   // [l*128+n] = b_{l+2}[n]*C2
  __shared__ __align__(16) unsigned short b5tab[2048]; // W5 A-frag image

  const int tid  = threadIdx.x;
  const int lane = tid & 63;
  const int wid  = tid >> 6;   // 0..3 : n-column group of 32
  const int lg   = lane >> 4;  // 0..3
  const int ln   = lane & 15;
  const int o    = tid >> 4;   // layer-1 n-octet 0..15
  const int c0   = tid & 15;   // layer-1 point-within-16

  const float Uval = Uin[0];
  const float b50  = b5[0];
  const float b51  = b5[1];

  // ---- stage LDS tables ----
  if (tid < 128) {
    w1tab[tid]       = W1[tid];
    w1tab[128 + tid] = W1[128 + tid];
    w1tab[256 + tid] = b1[tid];
    bctab[tid]       = b2[tid] * C2;
    bctab[128 + tid] = b3[tid] * C2;
    bctab[256 + tid] = b4[tid] * C2;
  }
  ((uint4*)b5tab)[tid] = ((const uint4*)(ws + 49152))[tid];

  // ---- W3,W4 A-fragments: opaque asm loads, pinned for the whole kernel ----
  s16x8 Wa3[2][4], Wa4[2][4];
#pragma unroll
  for (int nb = 0; nb < 2; ++nb)
#pragma unroll
    for (int kt = 0; kt < 4; ++kt) {
      unsigned voff3 = ((unsigned)(((1 * 8 + wid * 2 + nb) * 4 + kt)) << 10) + (unsigned)(lane * 16);
      unsigned voff4 = ((unsigned)(((2 * 8 + wid * 2 + nb) * 4 + kt)) << 10) + (unsigned)(lane * 16);
      asm volatile("global_load_dwordx4 %0, %1, %2"
                   : "=v"(Wa3[nb][kt]) : "v"(voff3), "s"(ws));
      asm volatile("global_load_dwordx4 %0, %1, %2"
                   : "=v"(Wa4[nb][kt]) : "v"(voff4), "s"(ws));
    }
  asm volatile("s_waitcnt vmcnt(0)");
  __builtin_amdgcn_sched_barrier(0);
  __syncthreads();   // tables staged

  // ---- LDS byte bases (all linear, no swizzle) ----
  const unsigned rBase  = (unsigned)(lane * 16);   // + mt*4096 + kt*1024
  const unsigned wBase0 = (unsigned)(wid * 1024 + (lg >> 1) * 256 + ln * 16 + (lg & 1) * 8);
  const unsigned wBase1 = wBase0 + 512;
  const unsigned l1Base = (unsigned)((o >> 2) * 1024 + (o & 3) * 256 + c0 * 16);

  for (int tile = blockIdx.x; tile < NTILE; tile += GRID) {
    const int pbase = tile << 6;

    // ---- stream this tile's W2 fragments (L1/L2-resident) ----
    s16x8 W2f[2][4];
#pragma unroll
    for (int nb = 0; nb < 2; ++nb)
#pragma unroll
      for (int kt = 0; kt < 4; ++kt)
        W2f[nb][kt] = *(const s16x8*)(ws + (((0 * 8 + wid * 2 + nb) * 4 + kt) << 9) + lane * 8);

    // ---- layer 1: h1 = tanh(xy@W1+b1) -> hbuf0 ----
    {
      const f32x4 wxa = *(const f32x4*)(w1tab + o * 8);
      const f32x4 wxb = *(const f32x4*)(w1tab + o * 8 + 4);
      const f32x4 wya = *(const f32x4*)(w1tab + 128 + o * 8);
      const f32x4 wyb = *(const f32x4*)(w1tab + 128 + o * 8 + 4);
      const f32x4 bba = *(const f32x4*)(w1tab + 256 + o * 8);
      const f32x4 bbb = *(const f32x4*)(w1tab + 256 + o * 8 + 4);
#pragma unroll
      for (int i = 0; i < 4; ++i) {
        int p = i * 16 + c0;
        float2 v = ((const float2*)xy)[pbase + p];
        unsigned q[4];
#pragma unroll
        for (int t2 = 0; t2 < 2; ++t2) {
          float s0 = fmaf(v.x, wxa[2 * t2],     fmaf(v.y, wya[2 * t2],     bba[2 * t2]));
          float s1 = fmaf(v.x, wxa[2 * t2 + 1], fmaf(v.y, wya[2 * t2 + 1], bba[2 * t2 + 1]));
          float e0 = __builtin_amdgcn_exp2f(s0 * C2);
          float e1 = __builtin_amdgcn_exp2f(s1 * C2);
          q[t2] = pack_bf16x2(1.0f - 2.0f * __builtin_amdgcn_rcpf(1.0f + e0),
                              1.0f - 2.0f * __builtin_amdgcn_rcpf(1.0f + e1));
        }
#pragma unroll
        for (int t2 = 0; t2 < 2; ++t2) {
          float s0 = fmaf(v.x, wxb[2 * t2],     fmaf(v.y, wyb[2 * t2],     bbb[2 * t2]));
          float s1 = fmaf(v.x, wxb[2 * t2 + 1], fmaf(v.y, wyb[2 * t2 + 1], bbb[2 * t2 + 1]));
          float e0 = __builtin_amdgcn_exp2f(s0 * C2);
          float e1 = __builtin_amdgcn_exp2f(s1 * C2);
          q[2 + t2] = pack_bf16x2(1.0f - 2.0f * __builtin_amdgcn_rcpf(1.0f + e0),
                                  1.0f - 2.0f * __builtin_amdgcn_rcpf(1.0f + e1));
        }
        *(uint4*)(hbuf0 + l1Base + i * 4096) = uint4{q[0], q[1], q[2], q[3]};
      }
    }
    __syncthreads();   // h1 visible (also drains W2f loads)

    // ---- layers 2..4 ----
    layer_fwd(W2f, hbuf0, hbuf1, bctab,       rBase, wBase0, wBase1, wid, lg);
    __syncthreads();
    layer_fwd(Wa3, hbuf1, hbuf0, bctab + 128, rBase, wBase0, wBase1, wid, lg);
    __syncthreads();
    layer_fwd(Wa4, hbuf0, hbuf1, bctab + 256, rBase, wBase0, wBase1, wid, lg);
    __syncthreads();

    // ---- layer 5 + epilogue (reads hbuf1 = L4 out; wave: 16 points, mt=wid) ----
    f32x4 acc5 = f32x4{0.f, 0.f, 0.f, 0.f};
#pragma unroll
    for (int kt = 0; kt < 4; ++kt) {
      s16x8 b5f = *(const s16x8*)(b5tab + kt * 512 + lane * 8);
      s16x8 b   = *(const s16x8*)(hbuf1 + rBase + wid * 4096 + kt * 1024);
      acc5 = __builtin_amdgcn_mfma_f32_16x16x32_bf16(b5f, b, acc5, 0, 0, 0);
    }
    if (lg == 0) {
      int p = pbase + wid * 16 + ln;
      float uh = acc5[0] + b50;
      float vh = acc5[1] + b51;
      float2 v = ((const float2*)xy)[p];
      float Bm = v.x * (1.0f - v.x) * v.y * (1.0f - v.y);
      float psi = sigm_fast(50.0f * (v.x - 0.05f)) * sigm_fast(50.0f * (0.95f - v.x));
      out[p]        = fmaf(Uval * v.y, psi, Bm * uh);
      out[NPTS + p] = Bm * vh;
    }
    // no trailing barrier: next L1 writes hbuf0 (last readers are behind the L4
    // barrier); next L2 writes hbuf1 after the post-L1 barrier, after L5 reads.
  }
}

extern "C" void kernel_launch(void* const* d_in, const int* in_sizes, int n_in,
                              void* d_out, int out_size, void* d_ws, size_t ws_size,
                              hipStream_t stream) {
  const float* xy = (const float*)d_in[0];
  const float* U  = (const float*)d_in[1];
  const float* W1 = (const float*)d_in[2];
  const float* b1 = (const float*)d_in[3];
  const float* W2 = (const float*)d_in[4];
  const float* b2 = (const float*)d_in[5];
  const float* W3 = (const float*)d_in[6];
  const float* b3 = (const float*)d_in[7];
  const float* W4 = (const float*)d_in[8];
  const float* b4 = (const float*)d_in[9];
  const float* W5 = (const float*)d_in[10];
  const float* b5 = (const float*)d_in[11];
  unsigned short* ws = (unsigned short*)d_ws;   // needs ~100 KB
  float* out = (float*)d_out;

  prep_kernel<<<200, 256, 0, stream>>>(W2, W3, W4, W5, ws);
  mlp_kernel<<<GRID, 256, 0, stream>>>(xy, U, W1, b1, b2, b3, b4, b5, ws, out);
}

// Round 15
// 199.554 us; speedup vs baseline: 1.0532x; 1.0532x over previous
//
#include <hip/hip_runtime.h>
#include <hip/hip_bf16.h>

#define NPTS  1048576
#define GRID  768
#define NTILE 16384  // NPTS / 64
#define C2    2.8853900817779268f   // 2*log2(e)

typedef __attribute__((ext_vector_type(8))) short  s16x8;
typedef __attribute__((ext_vector_type(4))) float  f32x4;

__device__ __forceinline__ unsigned short bf16r(float v) {
  unsigned u = __builtin_bit_cast(unsigned, v);
  return (unsigned short)((u + 0x7fffu + ((u >> 16) & 1u)) >> 16);
}
__device__ __forceinline__ unsigned pack_bf16x2(float lo, float hi) {
  __hip_bfloat162 h = __float22bfloat162_rn(float2{lo, hi});
  unsigned r;
  __builtin_memcpy(&r, &h, sizeof(r));
  return r;
}
// tanh(s) with bias pre-folded: bc = bias*C2  (trans ops are ~full-rate on gfx950)
__device__ __forceinline__ float tanh_e(float acc, float bc) {
  float e = __builtin_amdgcn_exp2f(fmaf(acc, C2, bc));
  return 1.0f - 2.0f * __builtin_amdgcn_rcpf(1.0f + e);
}
__device__ __forceinline__ float sigm_fast(float x) {
  return __builtin_amdgcn_rcpf(1.0f + __builtin_amdgcn_exp2f(x * -1.4426950408889634f));
}

// ws layout (u16 units) — W stored TRANSPOSED as MFMA A-fragments (natural n order):
//  [0 .. 49152)     : ws[((l*8 + nbg)*4 + kt)*512 + lane*8 + e] =
//                     bf16( W_{l+2}[k*128 + n] ), k = kt*32 + (lane>>4)*8 + e,
//                     n = nbg*16 + (lane&15);  l=0..2 (W2,W3,W4)
//  [49152 .. 51200) : W5 A-frag image: ws[49152 + kt*512 + lane*8 + e] =
//                     (lane&15)<2 ? bf16(W5[k*2 + (lane&15)]) : 0
__global__ void prep_kernel(const float* __restrict__ W2, const float* __restrict__ W3,
                            const float* __restrict__ W4, const float* __restrict__ W5,
                            unsigned short* __restrict__ ws)
{
  int tid = blockIdx.x * 256 + threadIdx.x;
  if (tid < 49152) {
    int l    = tid >> 14;
    int idx  = tid & 16383;
    int e    = idx & 7;
    int lane = (idx >> 3) & 63;
    int kt   = (idx >> 9) & 3;
    int nbg  = (idx >> 11) & 7;
    int k = kt * 32 + (lane >> 4) * 8 + e;
    int n = nbg * 16 + (lane & 15);
    const float* W = (l == 0) ? W2 : (l == 1) ? W3 : W4;
    ws[tid] = bf16r(W[k * 128 + n]);
  } else if (tid < 51200) {
    int idx  = tid - 49152;
    int e    = idx & 7;
    int lane = (idx >> 3) & 63;
    int kt   = idx >> 9;
    int k  = kt * 32 + (lane >> 4) * 8 + e;
    int nl = lane & 15;
    ws[tid] = (nl < 2) ? bf16r(W5[k * 2 + nl]) : (unsigned short)0;
  }
}

// one hidden layer: D = W^T·h^T, tanh, write back. WA bound statically via inlining.
__device__ __forceinline__ void layer_fwd(const s16x8 WA[2][4],
                                          const unsigned char* bufR, unsigned char* bufW,
                                          const float* bctab_l,
                                          unsigned rBase, unsigned wBase0, unsigned wBase1,
                                          int wid, int lg)
{
  const f32x4 bcl0 = *(const f32x4*)(bctab_l + wid * 32 + lg * 4);
  const f32x4 bcl1 = *(const f32x4*)(bctab_l + wid * 32 + 16 + lg * 4);
#pragma unroll
  for (int mt = 0; mt < 4; ++mt) {
    s16x8 B[4];
#pragma unroll
    for (int kt = 0; kt < 4; ++kt)
      B[kt] = *(const s16x8*)(bufR + rBase + mt * 4096 + kt * 1024);
    f32x4 acc0 = f32x4{0.f, 0.f, 0.f, 0.f};
    f32x4 acc1 = f32x4{0.f, 0.f, 0.f, 0.f};
#pragma unroll
    for (int kt = 0; kt < 4; ++kt) {
      acc0 = __builtin_amdgcn_mfma_f32_16x16x32_bf16(WA[0][kt], B[kt], acc0, 0, 0, 0);
      acc1 = __builtin_amdgcn_mfma_f32_16x16x32_bf16(WA[1][kt], B[kt], acc1, 0, 0, 0);
    }
    {
      float t0 = tanh_e(acc0[0], bcl0[0]);
      float t1 = tanh_e(acc0[1], bcl0[1]);
      float t2 = tanh_e(acc0[2], bcl0[2]);
      float t3 = tanh_e(acc0[3], bcl0[3]);
      *(uint2*)(bufW + wBase0 + mt * 4096) = uint2{pack_bf16x2(t0, t1), pack_bf16x2(t2, t3)};
    }
    {
      float t0 = tanh_e(acc1[0], bcl1[0]);
      float t1 = tanh_e(acc1[1], bcl1[1]);
      float t2 = tanh_e(acc1[2], bcl1[2]);
      float t3 = tanh_e(acc1[3], bcl1[3]);
      *(uint2*)(bufW + wBase1 + mt * 4096) = uint2{pack_bf16x2(t0, t1), pack_bf16x2(t2, t3)};
    }
  }
}

__global__ __launch_bounds__(256, 3)
void mlp_kernel(const float* __restrict__ xy, const float* __restrict__ Uin,
                const float* __restrict__ W1, const float* __restrict__ b1,
                const float* __restrict__ b2, const float* __restrict__ b3,
                const float* __restrict__ b4, const float* __restrict__ b5,
                const unsigned short* __restrict__ ws, float* __restrict__ out)
{
  // ping-pong h buffers, FRAGMENT-MAJOR, 64-point tile (mt=0..3):
  //   hbuf[(mt*4+kt)*1024 + lane*16 + e*2] = h[mt*16+(lane&15)][kt*32+(lane>>4)*8+e]
  __shared__ __align__(16) unsigned char hbuf0[16384];
  __shared__ __align__(16) unsigned char hbuf1[16384];
  __shared__ __align__(16) float         w1tab[384];   // w1x[128],w1y[128],b1[128]
  __shared__ __align__(16) float         bctab[384];   // [l*128+n] = b_{l+2}[n]*C2
  __shared__ __align__(16) unsigned short b5tab[2048]; // W5 A-frag image

  const int tid  = threadIdx.x;
  const int lane = tid & 63;
  const int wid  = tid >> 6;   // 0..3 : n-column group of 32
  const int lg   = lane >> 4;  // 0..3
  const int ln   = lane & 15;
  const int o    = tid >> 4;   // layer-1 n-octet 0..15
  const int c0   = tid & 15;   // layer-1 point-within-16

  const float Uval = Uin[0];
  const float b50  = b5[0];
  const float b51  = b5[1];

  // ---- stage LDS tables ----
  if (tid < 128) {
    w1tab[tid]       = W1[tid];
    w1tab[128 + tid] = W1[128 + tid];
    w1tab[256 + tid] = b1[tid];
    bctab[tid]       = b2[tid] * C2;
    bctab[128 + tid] = b3[tid] * C2;
    bctab[256 + tid] = b4[tid] * C2;
  }
  ((uint4*)b5tab)[tid] = ((const uint4*)(ws + 49152))[tid];

  // ---- W3,W4 A-fragments: opaque asm loads, pinned for the whole kernel ----
  s16x8 Wa3[2][4], Wa4[2][4];
#pragma unroll
  for (int nb = 0; nb < 2; ++nb)
#pragma unroll
    for (int kt = 0; kt < 4; ++kt) {
      unsigned voff3 = ((unsigned)(((1 * 8 + wid * 2 + nb) * 4 + kt)) << 10) + (unsigned)(lane * 16);
      unsigned voff4 = ((unsigned)(((2 * 8 + wid * 2 + nb) * 4 + kt)) << 10) + (unsigned)(lane * 16);
      asm volatile("global_load_dwordx4 %0, %1, %2"
                   : "=v"(Wa3[nb][kt]) : "v"(voff3), "s"(ws));
      asm volatile("global_load_dwordx4 %0, %1, %2"
                   : "=v"(Wa4[nb][kt]) : "v"(voff4), "s"(ws));
    }
  asm volatile("s_waitcnt vmcnt(0)");
  __builtin_amdgcn_sched_barrier(0);
  __syncthreads();   // tables staged

  // ---- LDS byte bases (all linear, no swizzle) ----
  const unsigned rBase  = (unsigned)(lane * 16);   // + mt*4096 + kt*1024
  const unsigned wBase0 = (unsigned)(wid * 1024 + (lg >> 1) * 256 + ln * 16 + (lg & 1) * 8);
  const unsigned wBase1 = wBase0 + 512;
  const unsigned l1Base = (unsigned)((o >> 2) * 1024 + (o & 3) * 256 + c0 * 16);

  for (int tile = blockIdx.x; tile < NTILE; tile += GRID) {
    const int pbase = tile << 6;

    // ---- stream this tile's W2 fragments (L1/L2-resident) ----
    s16x8 W2f[2][4];
#pragma unroll
    for (int nb = 0; nb < 2; ++nb)
#pragma unroll
      for (int kt = 0; kt < 4; ++kt)
        W2f[nb][kt] = *(const s16x8*)(ws + (((0 * 8 + wid * 2 + nb) * 4 + kt) << 9) + lane * 8);

    // ---- layer 1: h1 = tanh(xy@W1+b1) -> hbuf0 ----
    {
      const f32x4 wxa = *(const f32x4*)(w1tab + o * 8);
      const f32x4 wxb = *(const f32x4*)(w1tab + o * 8 + 4);
      const f32x4 wya = *(const f32x4*)(w1tab + 128 + o * 8);
      const f32x4 wyb = *(const f32x4*)(w1tab + 128 + o * 8 + 4);
      const f32x4 bba = *(const f32x4*)(w1tab + 256 + o * 8);
      const f32x4 bbb = *(const f32x4*)(w1tab + 256 + o * 8 + 4);
#pragma unroll
      for (int i = 0; i < 4; ++i) {
        int p = i * 16 + c0;
        float2 v = ((const float2*)xy)[pbase + p];
        unsigned q[4];
#pragma unroll
        for (int t2 = 0; t2 < 2; ++t2) {
          float s0 = fmaf(v.x, wxa[2 * t2],     fmaf(v.y, wya[2 * t2],     bba[2 * t2]));
          float s1 = fmaf(v.x, wxa[2 * t2 + 1], fmaf(v.y, wya[2 * t2 + 1], bba[2 * t2 + 1]));
          float e0 = __builtin_amdgcn_exp2f(s0 * C2);
          float e1 = __builtin_amdgcn_exp2f(s1 * C2);
          q[t2] = pack_bf16x2(1.0f - 2.0f * __builtin_amdgcn_rcpf(1.0f + e0),
                              1.0f - 2.0f * __builtin_amdgcn_rcpf(1.0f + e1));
        }
#pragma unroll
        for (int t2 = 0; t2 < 2; ++t2) {
          float s0 = fmaf(v.x, wxb[2 * t2],     fmaf(v.y, wyb[2 * t2],     bbb[2 * t2]));
          float s1 = fmaf(v.x, wxb[2 * t2 + 1], fmaf(v.y, wyb[2 * t2 + 1], bbb[2 * t2 + 1]));
          float e0 = __builtin_amdgcn_exp2f(s0 * C2);
          float e1 = __builtin_amdgcn_exp2f(s1 * C2);
          q[2 + t2] = pack_bf16x2(1.0f - 2.0f * __builtin_amdgcn_rcpf(1.0f + e0),
                                  1.0f - 2.0f * __builtin_amdgcn_rcpf(1.0f + e1));
        }
        *(uint4*)(hbuf0 + l1Base + i * 4096) = uint4{q[0], q[1], q[2], q[3]};
      }
    }
    __syncthreads();   // h1 visible (also drains W2f loads)

    // ---- layers 2..4 ----
    layer_fwd(W2f, hbuf0, hbuf1, bctab,       rBase, wBase0, wBase1, wid, lg);
    __syncthreads();
    layer_fwd(Wa3, hbuf1, hbuf0, bctab + 128, rBase, wBase0, wBase1, wid, lg);
    __syncthreads();
    layer_fwd(Wa4, hbuf0, hbuf1, bctab + 256, rBase, wBase0, wBase1, wid, lg);
    __syncthreads();

    // ---- layer 5 + epilogue (reads hbuf1 = L4 out; wave: 16 points, mt=wid) ----
    f32x4 acc5 = f32x4{0.f, 0.f, 0.f, 0.f};
#pragma unroll
    for (int kt = 0; kt < 4; ++kt) {
      s16x8 b5f = *(const s16x8*)(b5tab + kt * 512 + lane * 8);
      s16x8 b   = *(const s16x8*)(hbuf1 + rBase + wid * 4096 + kt * 1024);
      acc5 = __builtin_amdgcn_mfma_f32_16x16x32_bf16(b5f, b, acc5, 0, 0, 0);
    }
    if (lg == 0) {
      int p = pbase + wid * 16 + ln;
      float uh = acc5[0] + b50;
      float vh = acc5[1] + b51;
      float2 v = ((const float2*)xy)[p];
      float Bm = v.x * (1.0f - v.x) * v.y * (1.0f - v.y);
      float psi = sigm_fast(50.0f * (v.x - 0.05f)) * sigm_fast(50.0f * (0.95f - v.x));
      out[p]        = fmaf(Uval * v.y, psi, Bm * uh);
      out[NPTS + p] = Bm * vh;
    }
    // no trailing barrier: next L1 writes hbuf0 (last readers are behind the L4
    // barrier); next L2 writes hbuf1 after the post-L1 barrier, after L5 reads.
  }
}

extern "C" void kernel_launch(void* const* d_in, const int* in_sizes, int n_in,
                              void* d_out, int out_size, void* d_ws, size_t ws_size,
                              hipStream_t stream) {
  const float* xy = (const float*)d_in[0];
  const float* U  = (const float*)d_in[1];
  const float* W1 = (const float*)d_in[2];
  const float* b1 = (const float*)d_in[3];
  const float* W2 = (const float*)d_in[4];
  const float* b2 = (const float*)d_in[5];
  const float* W3 = (const float*)d_in[6];
  const float* b3 = (const float*)d_in[7];
  const float* W4 = (const float*)d_in[8];
  const float* b4 = (const float*)d_in[9];
  const float* W5 = (const float*)d_in[10];
  const float* b5 = (const float*)d_in[11];
  unsigned short* ws = (unsigned short*)d_ws;   // needs ~100 KB
  float* out = (float*)d_out;

  prep_kernel<<<200, 256, 0, stream>>>(W2, W3, W4, W5, ws);
  mlp_kernel<<<GRID, 256, 0, stream>>>(xy, U, W1, b1, b2, b3, b4, b5, ws, out);
}

// Round 16
// 175.454 us; speedup vs baseline: 1.1979x; 1.1374x over previous
//
#include <hip/hip_runtime.h>
#include <hip/hip_bf16.h>

#define NPTS  1048576
#define GRID  768
#define NTILE 16384  // NPTS / 64
#define C2    2.8853900817779268f   // 2*log2(e)

typedef __attribute__((ext_vector_type(8))) short  s16x8;
typedef __attribute__((ext_vector_type(4))) float  f32x4;

__device__ __forceinline__ unsigned short bf16r(float v) {
  unsigned u = __builtin_bit_cast(unsigned, v);
  return (unsigned short)((u + 0x7fffu + ((u >> 16) & 1u)) >> 16);
}
// single-instruction packed f32->bf16 (RNE). No builtin on gfx950 -> inline asm (T12).
__device__ __forceinline__ unsigned pack_bf16x2(float lo, float hi) {
  unsigned r;
  asm("v_cvt_pk_bf16_f32 %0, %1, %2" : "=v"(r) : "v"(lo), "v"(hi));
  return r;
}
// tanh(s) with bias pre-folded: bc = bias*C2
__device__ __forceinline__ float tanh_e(float acc, float bc) {
  float e = __builtin_amdgcn_exp2f(fmaf(acc, C2, bc));
  return 1.0f - 2.0f * __builtin_amdgcn_rcpf(1.0f + e);
}
__device__ __forceinline__ float sigm_fast(float x) {
  return __builtin_amdgcn_rcpf(1.0f + __builtin_amdgcn_exp2f(x * -1.4426950408889634f));
}

// ws layout (u16 units) — W stored TRANSPOSED as MFMA A-fragments (natural n order):
//  [0 .. 49152)     : ws[((l*8 + nbg)*4 + kt)*512 + lane*8 + e] =
//                     bf16( W_{l+2}[k*128 + n] ), k = kt*32 + (lane>>4)*8 + e,
//                     n = nbg*16 + (lane&15);  l=0..2 (W2,W3,W4)
//  [49152 .. 51200) : W5 A-frag image: ws[49152 + kt*512 + lane*8 + e] =
//                     (lane&15)<2 ? bf16(W5[k*2 + (lane&15)]) : 0
__global__ void prep_kernel(const float* __restrict__ W2, const float* __restrict__ W3,
                            const float* __restrict__ W4, const float* __restrict__ W5,
                            unsigned short* __restrict__ ws)
{
  int tid = blockIdx.x * 256 + threadIdx.x;
  if (tid < 49152) {
    int l    = tid >> 14;
    int idx  = tid & 16383;
    int e    = idx & 7;
    int lane = (idx >> 3) & 63;
    int kt   = (idx >> 9) & 3;
    int nbg  = (idx >> 11) & 7;
    int k = kt * 32 + (lane >> 4) * 8 + e;
    int n = nbg * 16 + (lane & 15);
    const float* W = (l == 0) ? W2 : (l == 1) ? W3 : W4;
    ws[tid] = bf16r(W[k * 128 + n]);
  } else if (tid < 51200) {
    int idx  = tid - 49152;
    int e    = idx & 7;
    int lane = (idx >> 3) & 63;
    int kt   = idx >> 9;
    int k  = kt * 32 + (lane >> 4) * 8 + e;
    int nl = lane & 15;
    ws[tid] = (nl < 2) ? bf16r(W5[k * 2 + nl]) : (unsigned short)0;
  }
}

// one hidden layer: D = W^T·h^T, tanh, write back. WA bound statically via inlining.
__device__ __forceinline__ void layer_fwd(const s16x8 WA[2][4],
                                          const unsigned char* bufR, unsigned char* bufW,
                                          const float* bctab_l,
                                          unsigned rBase, unsigned wBase0, unsigned wBase1,
                                          int wid, int lg)
{
  const f32x4 bcl0 = *(const f32x4*)(bctab_l + wid * 32 + lg * 4);
  const f32x4 bcl1 = *(const f32x4*)(bctab_l + wid * 32 + 16 + lg * 4);
#pragma unroll
  for (int mt = 0; mt < 4; ++mt) {
    s16x8 B[4];
#pragma unroll
    for (int kt = 0; kt < 4; ++kt)
      B[kt] = *(const s16x8*)(bufR + rBase + mt * 4096 + kt * 1024);
    f32x4 acc0 = f32x4{0.f, 0.f, 0.f, 0.f};
    f32x4 acc1 = f32x4{0.f, 0.f, 0.f, 0.f};
#pragma unroll
    for (int kt = 0; kt < 4; ++kt) {
      acc0 = __builtin_amdgcn_mfma_f32_16x16x32_bf16(WA[0][kt], B[kt], acc0, 0, 0, 0);
      acc1 = __builtin_amdgcn_mfma_f32_16x16x32_bf16(WA[1][kt], B[kt], acc1, 0, 0, 0);
    }
    {
      float t0 = tanh_e(acc0[0], bcl0[0]);
      float t1 = tanh_e(acc0[1], bcl0[1]);
      float t2 = tanh_e(acc0[2], bcl0[2]);
      float t3 = tanh_e(acc0[3], bcl0[3]);
      *(uint2*)(bufW + wBase0 + mt * 4096) = uint2{pack_bf16x2(t0, t1), pack_bf16x2(t2, t3)};
    }
    {
      float t0 = tanh_e(acc1[0], bcl1[0]);
      float t1 = tanh_e(acc1[1], bcl1[1]);
      float t2 = tanh_e(acc1[2], bcl1[2]);
      float t3 = tanh_e(acc1[3], bcl1[3]);
      *(uint2*)(bufW + wBase1 + mt * 4096) = uint2{pack_bf16x2(t0, t1), pack_bf16x2(t2, t3)};
    }
  }
}

__global__ __launch_bounds__(256, 3)
void mlp_kernel(const float* __restrict__ xy, const float* __restrict__ Uin,
                const float* __restrict__ W1, const float* __restrict__ b1,
                const float* __restrict__ b2, const float* __restrict__ b3,
                const float* __restrict__ b4, const float* __restrict__ b5,
                const unsigned short* __restrict__ ws, float* __restrict__ out)
{
  // ping-pong h buffers, FRAGMENT-MAJOR, 64-point tile (mt=0..3):
  //   hbuf[(mt*4+kt)*1024 + lane*16 + e*2] = h[mt*16+(lane&15)][kt*32+(lane>>4)*8+e]
  __shared__ __align__(16) unsigned char hbuf0[16384];
  __shared__ __align__(16) unsigned char hbuf1[16384];
  __shared__ __align__(16) float         w1tab[384];   // w1x[128],w1y[128],b1[128]
  __shared__ __align__(16) float         bctab[384];   // [l*128+n] = b_{l+2}[n]*C2
  __shared__ __align__(16) unsigned short b5tab[2048]; // W5 A-frag image

  const int tid  = threadIdx.x;
  const int lane = tid & 63;
  const int wid  = tid >> 6;   // 0..3 : n-column group of 32
  const int lg   = lane >> 4;  // 0..3
  const int ln   = lane & 15;
  const int o    = tid >> 4;   // layer-1 n-octet 0..15
  const int c0   = tid & 15;   // layer-1 point-within-16

  const float Uval = Uin[0];
  const float b50  = b5[0];
  const float b51  = b5[1];

  // ---- stage LDS tables ----
  if (tid < 128) {
    w1tab[tid]       = W1[tid];
    w1tab[128 + tid] = W1[128 + tid];
    w1tab[256 + tid] = b1[tid];
    bctab[tid]       = b2[tid] * C2;
    bctab[128 + tid] = b3[tid] * C2;
    bctab[256 + tid] = b4[tid] * C2;
  }
  ((uint4*)b5tab)[tid] = ((const uint4*)(ws + 49152))[tid];

  // ---- W3,W4 A-fragments: opaque asm loads, pinned for the whole kernel ----
  s16x8 Wa3[2][4], Wa4[2][4];
#pragma unroll
  for (int nb = 0; nb < 2; ++nb)
#pragma unroll
    for (int kt = 0; kt < 4; ++kt) {
      unsigned voff3 = ((unsigned)(((1 * 8 + wid * 2 + nb) * 4 + kt)) << 10) + (unsigned)(lane * 16);
      unsigned voff4 = ((unsigned)(((2 * 8 + wid * 2 + nb) * 4 + kt)) << 10) + (unsigned)(lane * 16);
      asm volatile("global_load_dwordx4 %0, %1, %2"
                   : "=v"(Wa3[nb][kt]) : "v"(voff3), "s"(ws));
      asm volatile("global_load_dwordx4 %0, %1, %2"
                   : "=v"(Wa4[nb][kt]) : "v"(voff4), "s"(ws));
    }
  asm volatile("s_waitcnt vmcnt(0)");
  __builtin_amdgcn_sched_barrier(0);
  __syncthreads();   // tables staged

  // ---- LDS byte bases (all linear, no swizzle) ----
  const unsigned rBase  = (unsigned)(lane * 16);   // + mt*4096 + kt*1024
  const unsigned wBase0 = (unsigned)(wid * 1024 + (lg >> 1) * 256 + ln * 16 + (lg & 1) * 8);
  const unsigned wBase1 = wBase0 + 512;
  const unsigned l1Base = (unsigned)((o >> 2) * 1024 + (o & 3) * 256 + c0 * 16);

  for (int tile = blockIdx.x; tile < NTILE; tile += GRID) {
    const int pbase = tile << 6;

    // ---- stream this tile's W2 fragments (L1/L2-resident) ----
    s16x8 W2f[2][4];
#pragma unroll
    for (int nb = 0; nb < 2; ++nb)
#pragma unroll
      for (int kt = 0; kt < 4; ++kt)
        W2f[nb][kt] = *(const s16x8*)(ws + (((0 * 8 + wid * 2 + nb) * 4 + kt) << 9) + lane * 8);

    // ---- layer 1: h1 = tanh(xy@W1+b1) -> hbuf0 ----
    {
      const f32x4 wxa = *(const f32x4*)(w1tab + o * 8);
      const f32x4 wxb = *(const f32x4*)(w1tab + o * 8 + 4);
      const f32x4 wya = *(const f32x4*)(w1tab + 128 + o * 8);
      const f32x4 wyb = *(const f32x4*)(w1tab + 128 + o * 8 + 4);
      const f32x4 bba = *(const f32x4*)(w1tab + 256 + o * 8);
      const f32x4 bbb = *(const f32x4*)(w1tab + 256 + o * 8 + 4);
#pragma unroll
      for (int i = 0; i < 4; ++i) {
        int p = i * 16 + c0;
        float2 v = ((const float2*)xy)[pbase + p];
        unsigned q[4];
#pragma unroll
        for (int t2 = 0; t2 < 2; ++t2) {
          float s0 = fmaf(v.x, wxa[2 * t2],     fmaf(v.y, wya[2 * t2],     bba[2 * t2]));
          float s1 = fmaf(v.x, wxa[2 * t2 + 1], fmaf(v.y, wya[2 * t2 + 1], bba[2 * t2 + 1]));
          float e0 = __builtin_amdgcn_exp2f(s0 * C2);
          float e1 = __builtin_amdgcn_exp2f(s1 * C2);
          q[t2] = pack_bf16x2(1.0f - 2.0f * __builtin_amdgcn_rcpf(1.0f + e0),
                              1.0f - 2.0f * __builtin_amdgcn_rcpf(1.0f + e1));
        }
#pragma unroll
        for (int t2 = 0; t2 < 2; ++t2) {
          float s0 = fmaf(v.x, wxb[2 * t2],     fmaf(v.y, wyb[2 * t2],     bbb[2 * t2]));
          float s1 = fmaf(v.x, wxb[2 * t2 + 1], fmaf(v.y, wyb[2 * t2 + 1], bbb[2 * t2 + 1]));
          float e0 = __builtin_amdgcn_exp2f(s0 * C2);
          float e1 = __builtin_amdgcn_exp2f(s1 * C2);
          q[2 + t2] = pack_bf16x2(1.0f - 2.0f * __builtin_amdgcn_rcpf(1.0f + e0),
                                  1.0f - 2.0f * __builtin_amdgcn_rcpf(1.0f + e1));
        }
        *(uint4*)(hbuf0 + l1Base + i * 4096) = uint4{q[0], q[1], q[2], q[3]};
      }
    }
    __syncthreads();   // h1 visible (also drains W2f loads)

    // ---- layers 2..4 ----
    layer_fwd(W2f, hbuf0, hbuf1, bctab,       rBase, wBase0, wBase1, wid, lg);
    __syncthreads();
    layer_fwd(Wa3, hbuf1, hbuf0, bctab + 128, rBase, wBase0, wBase1, wid, lg);
    __syncthreads();
    layer_fwd(Wa4, hbuf0, hbuf1, bctab + 256, rBase, wBase0, wBase1, wid, lg);
    __syncthreads();

    // ---- layer 5 + epilogue (reads hbuf1 = L4 out; wave: 16 points, mt=wid) ----
    f32x4 acc5 = f32x4{0.f, 0.f, 0.f, 0.f};
#pragma unroll
    for (int kt = 0; kt < 4; ++kt) {
      s16x8 b5f = *(const s16x8*)(b5tab + kt * 512 + lane * 8);
      s16x8 b   = *(const s16x8*)(hbuf1 + rBase + wid * 4096 + kt * 1024);
      acc5 = __builtin_amdgcn_mfma_f32_16x16x32_bf16(b5f, b, acc5, 0, 0, 0);
    }
    if (lg == 0) {
      int p = pbase + wid * 16 + ln;
      float uh = acc5[0] + b50;
      float vh = acc5[1] + b51;
      float2 v = ((const float2*)xy)[p];
      float Bm = v.x * (1.0f - v.x) * v.y * (1.0f - v.y);
      float psi = sigm_fast(50.0f * (v.x - 0.05f)) * sigm_fast(50.0f * (0.95f - v.x));
      out[p]        = fmaf(Uval * v.y, psi, Bm * uh);
      out[NPTS + p] = Bm * vh;
    }
    // no trailing barrier: next L1 writes hbuf0 (last readers are behind the L4
    // barrier); next L2 writes hbuf1 after the post-L1 barrier, after L5 reads.
  }
}

extern "C" void kernel_launch(void* const* d_in, const int* in_sizes, int n_in,
                              void* d_out, int out_size, void* d_ws, size_t ws_size,
                              hipStream_t stream) {
  const float* xy = (const float*)d_in[0];
  const float* U  = (const float*)d_in[1];
  const float* W1 = (const float*)d_in[2];
  const float* b1 = (const float*)d_in[3];
  const float* W2 = (const float*)d_in[4];
  const float* b2 = (const float*)d_in[5];
  const float* W3 = (const float*)d_in[6];
  const float* b3 = (const float*)d_in[7];
  const float* W4 = (const float*)d_in[8];
  const float* b4 = (const float*)d_in[9];
  const float* W5 = (const float*)d_in[10];
  const float* b5 = (const float*)d_in[11];
  unsigned short* ws = (unsigned short*)d_ws;   // needs ~100 KB
  float* out = (float*)d_out;

  prep_kernel<<<200, 256, 0, stream>>>(W2, W3, W4, W5, ws);
  mlp_kernel<<<GRID, 256, 0, stream>>>(xy, U, W1, b1, b2, b3, b4, b5, ws, out);
}

// Round 21
// 171.395 us; speedup vs baseline: 1.2263x; 1.0237x over previous
//
#include <hip/hip_runtime.h>
#include <hip/hip_bf16.h>

#define NPTS  1048576
#define GRID  768
#define NTILE 16384  // NPTS / 64
#define C2    2.8853900817779268f   // 2*log2(e)

typedef __attribute__((ext_vector_type(8))) short  s16x8;
typedef __attribute__((ext_vector_type(4))) float  f32x4;
typedef __attribute__((ext_vector_type(2))) float  f32x2;

__device__ __forceinline__ unsigned short bf16r(float v) {
  unsigned u = __builtin_bit_cast(unsigned, v);
  return (unsigned short)((u + 0x7fffu + ((u >> 16) & 1u)) >> 16);
}
// packed tanh -> packed bf16, input pre-scaled by C2 (s2 = C2*x):
// e=exp2(s); o = 1 - 2*rcp(1+e). Vector C ops -> compiler may select v_pk_*;
// falls back to scalar pairs (correct either way). cvt_pk asm proven in r16.
__device__ __forceinline__ unsigned tanh2_pre(f32x2 s2) {
  f32x2 e2 = { __builtin_amdgcn_exp2f(s2.x), __builtin_amdgcn_exp2f(s2.y) };
  f32x2 d2 = e2 + 1.0f;
  f32x2 r2 = { __builtin_amdgcn_rcpf(d2.x), __builtin_amdgcn_rcpf(d2.y) };
  f32x2 o2 = __builtin_elementwise_fma(r2, f32x2{-2.0f, -2.0f}, f32x2{1.0f, 1.0f});
  unsigned q;
  asm("v_cvt_pk_bf16_f32 %0, %1, %2" : "=v"(q) : "v"(o2.x), "v"(o2.y));
  return q;
}
// packed tanh for raw MFMA acc pair: s2 = a*C2 + bc (bc = bias*C2)
__device__ __forceinline__ unsigned tanh2_acc(float a0, float a1, f32x2 bc2) {
  f32x2 a2 = { a0, a1 };
  f32x2 s2 = __builtin_elementwise_fma(a2, f32x2{C2, C2}, bc2);
  return tanh2_pre(s2);
}
__device__ __forceinline__ float sigm_fast(float x) {
  return __builtin_amdgcn_rcpf(1.0f + __builtin_amdgcn_exp2f(x * -1.4426950408889634f));
}

// ws layout (u16 units) — W stored TRANSPOSED as MFMA A-fragments (natural n order):
//  [0 .. 49152)     : ws[((l*8 + nbg)*4 + kt)*512 + lane*8 + e] =
//                     bf16( W_{l+2}[k*128 + n] ), k = kt*32 + (lane>>4)*8 + e,
//                     n = nbg*16 + (lane&15);  l=0..2 (W2,W3,W4)
//  [49152 .. 51200) : W5 A-frag image: ws[49152 + kt*512 + lane*8 + e] =
//                     (lane&15)<2 ? bf16(W5[k*2 + (lane&15)]) : 0
__global__ void prep_kernel(const float* __restrict__ W2, const float* __restrict__ W3,
                            const float* __restrict__ W4, const float* __restrict__ W5,
                            unsigned short* __restrict__ ws)
{
  int tid = blockIdx.x * 256 + threadIdx.x;
  if (tid < 49152) {
    int l    = tid >> 14;
    int idx  = tid & 16383;
    int e    = idx & 7;
    int lane = (idx >> 3) & 63;
    int kt   = (idx >> 9) & 3;
    int nbg  = (idx >> 11) & 7;
    int k = kt * 32 + (lane >> 4) * 8 + e;
    int n = nbg * 16 + (lane & 15);
    const float* W = (l == 0) ? W2 : (l == 1) ? W3 : W4;
    ws[tid] = bf16r(W[k * 128 + n]);
  } else if (tid < 51200) {
    int idx  = tid - 49152;
    int e    = idx & 7;
    int lane = (idx >> 3) & 63;
    int kt   = idx >> 9;
    int k  = kt * 32 + (lane >> 4) * 8 + e;
    int nl = lane & 15;
    ws[tid] = (nl < 2) ? bf16r(W5[k * 2 + nl]) : (unsigned short)0;
  }
}

// one hidden layer: D = W^T·h^T, tanh, write back. WA bound statically via inlining.
__device__ __forceinline__ void layer_fwd(const s16x8 WA[2][4],
                                          const unsigned char* bufR, unsigned char* bufW,
                                          const float* bctab_l,
                                          unsigned rBase, unsigned wBase0, unsigned wBase1,
                                          int wid, int lg)
{
  const f32x4 bcl0 = *(const f32x4*)(bctab_l + wid * 32 + lg * 4);
  const f32x4 bcl1 = *(const f32x4*)(bctab_l + wid * 32 + 16 + lg * 4);
#pragma unroll
  for (int mt = 0; mt < 4; ++mt) {
    s16x8 B[4];
#pragma unroll
    for (int kt = 0; kt < 4; ++kt)
      B[kt] = *(const s16x8*)(bufR + rBase + mt * 4096 + kt * 1024);
    f32x4 acc0 = f32x4{0.f, 0.f, 0.f, 0.f};
    f32x4 acc1 = f32x4{0.f, 0.f, 0.f, 0.f};
#pragma unroll
    for (int kt = 0; kt < 4; ++kt) {
      acc0 = __builtin_amdgcn_mfma_f32_16x16x32_bf16(WA[0][kt], B[kt], acc0, 0, 0, 0);
      acc1 = __builtin_amdgcn_mfma_f32_16x16x32_bf16(WA[1][kt], B[kt], acc1, 0, 0, 0);
    }
    {
      unsigned q01 = tanh2_acc(acc0[0], acc0[1], f32x2{bcl0[0], bcl0[1]});
      unsigned q23 = tanh2_acc(acc0[2], acc0[3], f32x2{bcl0[2], bcl0[3]});
      *(uint2*)(bufW + wBase0 + mt * 4096) = uint2{q01, q23};
    }
    {
      unsigned q01 = tanh2_acc(acc1[0], acc1[1], f32x2{bcl1[0], bcl1[1]});
      unsigned q23 = tanh2_acc(acc1[2], acc1[3], f32x2{bcl1[2], bcl1[3]});
      *(uint2*)(bufW + wBase1 + mt * 4096) = uint2{q01, q23};
    }
  }
}

__global__ __launch_bounds__(256, 3)
void mlp_kernel(const float* __restrict__ xy, const float* __restrict__ Uin,
                const float* __restrict__ W1, const float* __restrict__ b1,
                const float* __restrict__ b2, const float* __restrict__ b3,
                const float* __restrict__ b4, const float* __restrict__ b5,
                const unsigned short* __restrict__ ws, float* __restrict__ out)
{
  // ping-pong h buffers, FRAGMENT-MAJOR, 64-point tile (mt=0..3):
  //   hbuf[(mt*4+kt)*1024 + lane*16 + e*2] = h[mt*16+(lane&15)][kt*32+(lane>>4)*8+e]
  __shared__ __align__(16) unsigned char hbuf0[16384];
  __shared__ __align__(16) unsigned char hbuf1[16384];
  __shared__ __align__(16) float         w1tab[384];   // C2-prescaled w1x,w1y,b1
  __shared__ __align__(16) float         bctab[384];   // [l*128+n] = b_{l+2}[n]*C2
  __shared__ __align__(16) unsigned short b5tab[2048]; // W5 A-frag image

  const int tid  = threadIdx.x;
  const int lane = tid & 63;
  const int wid  = tid >> 6;   // 0..3 : n-column group of 32
  const int lg   = lane >> 4;  // 0..3
  const int ln   = lane & 15;
  const int o    = tid >> 4;   // layer-1 n-octet 0..15
  const int c0   = tid & 15;   // layer-1 point-within-16

  const float Uval = Uin[0];
  const float b50  = b5[0];
  const float b51  = b5[1];

  // ---- stage LDS tables (layer-1 tables PRE-SCALED by C2) ----
  if (tid < 128) {
    w1tab[tid]       = W1[tid] * C2;
    w1tab[128 + tid] = W1[128 + tid] * C2;
    w1tab[256 + tid] = b1[tid] * C2;
    bctab[tid]       = b2[tid] * C2;
    bctab[128 + tid] = b3[tid] * C2;
    bctab[256 + tid] = b4[tid] * C2;
  }
  ((uint4*)b5tab)[tid] = ((const uint4*)(ws + 49152))[tid];

  // ---- W3,W4 A-fragments: opaque asm loads, pinned for the whole kernel ----
  s16x8 Wa3[2][4], Wa4[2][4];
#pragma unroll
  for (int nb = 0; nb < 2; ++nb)
#pragma unroll
    for (int kt = 0; kt < 4; ++kt) {
      unsigned voff3 = ((unsigned)(((1 * 8 + wid * 2 + nb) * 4 + kt)) << 10) + (unsigned)(lane * 16);
      unsigned voff4 = ((unsigned)(((2 * 8 + wid * 2 + nb) * 4 + kt)) << 10) + (unsigned)(lane * 16);
      asm volatile("global_load_dwordx4 %0, %1, %2"
                   : "=v"(Wa3[nb][kt]) : "v"(voff3), "s"(ws));
      asm volatile("global_load_dwordx4 %0, %1, %2"
                   : "=v"(Wa4[nb][kt]) : "v"(voff4), "s"(ws));
    }
  asm volatile("s_waitcnt vmcnt(0)");
  __builtin_amdgcn_sched_barrier(0);
  __syncthreads();   // tables staged

  // ---- LDS byte bases (all linear, no swizzle) ----
  const unsigned rBase  = (unsigned)(lane * 16);   // + mt*4096 + kt*1024
  const unsigned wBase0 = (unsigned)(wid * 1024 + (lg >> 1) * 256 + ln * 16 + (lg & 1) * 8);
  const unsigned wBase1 = wBase0 + 512;
  const unsigned l1Base = (unsigned)((o >> 2) * 1024 + (o & 3) * 256 + c0 * 16);

  for (int tile = blockIdx.x; tile < NTILE; tile += GRID) {
    const int pbase = tile << 6;

    // ---- stream this tile's W2 fragments (L1/L2-resident) ----
    s16x8 W2f[2][4];
#pragma unroll
    for (int nb = 0; nb < 2; ++nb)
#pragma unroll
      for (int kt = 0; kt < 4; ++kt)
        W2f[nb][kt] = *(const s16x8*)(ws + (((0 * 8 + wid * 2 + nb) * 4 + kt) << 9) + lane * 8);

    // ---- layer 1: h1 = tanh(xy@W1+b1) -> hbuf0 (tables pre-scaled by C2) ----
    {
      const f32x4 wxa = *(const f32x4*)(w1tab + o * 8);
      const f32x4 wxb = *(const f32x4*)(w1tab + o * 8 + 4);
      const f32x4 wya = *(const f32x4*)(w1tab + 128 + o * 8);
      const f32x4 wyb = *(const f32x4*)(w1tab + 128 + o * 8 + 4);
      const f32x4 bba = *(const f32x4*)(w1tab + 256 + o * 8);
      const f32x4 bbb = *(const f32x4*)(w1tab + 256 + o * 8 + 4);
#pragma unroll
      for (int i = 0; i < 4; ++i) {
        int p = i * 16 + c0;
        float2 v = ((const float2*)xy)[pbase + p];
        unsigned q[4];
#pragma unroll
        for (int t2 = 0; t2 < 2; ++t2) {
          f32x2 s2 = { fmaf(v.x, wxa[2 * t2],     fmaf(v.y, wya[2 * t2],     bba[2 * t2])),
                       fmaf(v.x, wxa[2 * t2 + 1], fmaf(v.y, wya[2 * t2 + 1], bba[2 * t2 + 1])) };
          q[t2] = tanh2_pre(s2);
        }
#pragma unroll
        for (int t2 = 0; t2 < 2; ++t2) {
          f32x2 s2 = { fmaf(v.x, wxb[2 * t2],     fmaf(v.y, wyb[2 * t2],     bbb[2 * t2])),
                       fmaf(v.x, wxb[2 * t2 + 1], fmaf(v.y, wyb[2 * t2 + 1], bbb[2 * t2 + 1])) };
          q[2 + t2] = tanh2_pre(s2);
        }
        *(uint4*)(hbuf0 + l1Base + i * 4096) = uint4{q[0], q[1], q[2], q[3]};
      }
    }
    __syncthreads();   // h1 visible (also drains W2f loads)

    // ---- layers 2..4 ----
    layer_fwd(W2f, hbuf0, hbuf1, bctab,       rBase, wBase0, wBase1, wid, lg);
    __syncthreads();
    layer_fwd(Wa3, hbuf1, hbuf0, bctab + 128, rBase, wBase0, wBase1, wid, lg);
    __syncthreads();
    layer_fwd(Wa4, hbuf0, hbuf1, bctab + 256, rBase, wBase0, wBase1, wid, lg);
    __syncthreads();

    // ---- layer 5 + epilogue (reads hbuf1 = L4 out; wave: 16 points, mt=wid) ----
    f32x4 acc5 = f32x4{0.f, 0.f, 0.f, 0.f};
#pragma unroll
    for (int kt = 0; kt < 4; ++kt) {
      s16x8 b5f = *(const s16x8*)(b5tab + kt * 512 + lane * 8);
      s16x8 b   = *(const s16x8*)(hbuf1 + rBase + wid * 4096 + kt * 1024);
      acc5 = __builtin_amdgcn_mfma_f32_16x16x32_bf16(b5f, b, acc5, 0, 0, 0);
    }
    if (lg == 0) {
      int p = pbase + wid * 16 + ln;
      float uh = acc5[0] + b50;
      float vh = acc5[1] + b51;
      float2 v = ((const float2*)xy)[p];
      float Bm = v.x * (1.0f - v.x) * v.y * (1.0f - v.y);
      float psi = sigm_fast(50.0f * (v.x - 0.05f)) * sigm_fast(50.0f * (0.95f - v.x));
      out[p]        = fmaf(Uval * v.y, psi, Bm * uh);
      out[NPTS + p] = Bm * vh;
    }
    // no trailing barrier: next L1 writes hbuf0 (last readers are behind the L4
    // barrier); next L2 writes hbuf1 after the post-L1 barrier, after L5 reads.
  }
}

extern "C" void kernel_launch(void* const* d_in, const int* in_sizes, int n_in,
                              void* d_out, int out_size, void* d_ws, size_t ws_size,
                              hipStream_t stream) {
  const float* xy = (const float*)d_in[0];
  const float* U  = (const float*)d_in[1];
  const float* W1 = (const float*)d_in[2];
  const float* b1 = (const float*)d_in[3];
  const float* W2 = (const float*)d_in[4];
  const float* b2 = (const float*)d_in[5];
  const float* W3 = (const float*)d_in[6];
  const float* b3 = (const float*)d_in[7];
  const float* W4 = (const float*)d_in[8];
  const float* b4 = (const float*)d_in[9];
  const float* W5 = (const float*)d_in[10];
  const float* b5 = (const float*)d_in[11];
  unsigned short* ws = (unsigned short*)d_ws;   // needs ~100 KB
  float* out = (float*)d_out;

  prep_kernel<<<200, 256, 0, stream>>>(W2, W3, W4, W5, ws);
  mlp_kernel<<<GRID, 256, 0, stream>>>(xy, U, W1, b1, b2, b3, b4, b5, ws, out);
}

// Round 22
// 170.128 us; speedup vs baseline: 1.2354x; 1.0074x over previous
//
#include <hip/hip_runtime.h>
#include <hip/hip_bf16.h>

#define NPTS  1048576
#define GRID  768
#define NTILE 16384  // NPTS / 64
#define C2    2.8853900817779268f   // 2*log2(e)

typedef __attribute__((ext_vector_type(8))) short  s16x8;
typedef __attribute__((ext_vector_type(4))) float  f32x4;
typedef __attribute__((ext_vector_type(2))) float  f32x2;

__device__ __forceinline__ unsigned short bf16r(float v) {
  unsigned u = __builtin_bit_cast(unsigned, v);
  return (unsigned short)((u + 0x7fffu + ((u >> 16) & 1u)) >> 16);
}
// packed tanh -> packed bf16, input pre-scaled by C2 (s2 = C2*x):
// e=exp2(s); o = 1 - 2*rcp(1+e). Vector C ops -> compiler selects v_pk_* where
// legal; falls back to scalar pairs (correct either way). cvt_pk asm proven r16.
__device__ __forceinline__ unsigned tanh2_pre(f32x2 s2) {
  f32x2 e2 = { __builtin_amdgcn_exp2f(s2.x), __builtin_amdgcn_exp2f(s2.y) };
  f32x2 d2 = e2 + 1.0f;
  f32x2 r2 = { __builtin_amdgcn_rcpf(d2.x), __builtin_amdgcn_rcpf(d2.y) };
  f32x2 o2 = __builtin_elementwise_fma(r2, f32x2{-2.0f, -2.0f}, f32x2{1.0f, 1.0f});
  unsigned q;
  asm("v_cvt_pk_bf16_f32 %0, %1, %2" : "=v"(q) : "v"(o2.x), "v"(o2.y));
  return q;
}
// packed tanh for raw MFMA acc pair: s2 = a*C2 + bc (bc = bias*C2)
__device__ __forceinline__ unsigned tanh2_acc(float a0, float a1, f32x2 bc2) {
  f32x2 a2 = { a0, a1 };
  f32x2 s2 = __builtin_elementwise_fma(a2, f32x2{C2, C2}, bc2);
  return tanh2_pre(s2);
}
__device__ __forceinline__ float sigm_fast(float x) {
  return __builtin_amdgcn_rcpf(1.0f + __builtin_amdgcn_exp2f(x * -1.4426950408889634f));
}

// ws layout (u16 units) — W stored TRANSPOSED as MFMA A-fragments (natural n order):
//  [0 .. 49152)     : ws[((l*8 + nbg)*4 + kt)*512 + lane*8 + e] =
//                     bf16( W_{l+2}[k*128 + n] ), k = kt*32 + (lane>>4)*8 + e,
//                     n = nbg*16 + (lane&15);  l=0..2 (W2,W3,W4)
//  [49152 .. 51200) : W5 A-frag image: ws[49152 + kt*512 + lane*8 + e] =
//                     (lane&15)<2 ? bf16(W5[k*2 + (lane&15)]) : 0
__global__ void prep_kernel(const float* __restrict__ W2, const float* __restrict__ W3,
                            const float* __restrict__ W4, const float* __restrict__ W5,
                            unsigned short* __restrict__ ws)
{
  int tid = blockIdx.x * 256 + threadIdx.x;
  if (tid < 49152) {
    int l    = tid >> 14;
    int idx  = tid & 16383;
    int e    = idx & 7;
    int lane = (idx >> 3) & 63;
    int kt   = (idx >> 9) & 3;
    int nbg  = (idx >> 11) & 7;
    int k = kt * 32 + (lane >> 4) * 8 + e;
    int n = nbg * 16 + (lane & 15);
    const float* W = (l == 0) ? W2 : (l == 1) ? W3 : W4;
    ws[tid] = bf16r(W[k * 128 + n]);
  } else if (tid < 51200) {
    int idx  = tid - 49152;
    int e    = idx & 7;
    int lane = (idx >> 3) & 63;
    int kt   = idx >> 9;
    int k  = kt * 32 + (lane >> 4) * 8 + e;
    int nl = lane & 15;
    ws[tid] = (nl < 2) ? bf16r(W5[k * 2 + nl]) : (unsigned short)0;
  }
}

// one hidden layer: D = W^T·h^T, tanh, write back. WA bound statically via inlining.
__device__ __forceinline__ void layer_fwd(const s16x8 WA[2][4],
                                          const unsigned char* bufR, unsigned char* bufW,
                                          const float* bctab_l,
                                          unsigned rBase, unsigned wBase0, unsigned wBase1,
                                          int wid, int lg)
{
  const f32x4 bcl0 = *(const f32x4*)(bctab_l + wid * 32 + lg * 4);
  const f32x4 bcl1 = *(const f32x4*)(bctab_l + wid * 32 + 16 + lg * 4);
#pragma unroll
  for (int mt = 0; mt < 4; ++mt) {
    s16x8 B[4];
#pragma unroll
    for (int kt = 0; kt < 4; ++kt)
      B[kt] = *(const s16x8*)(bufR + rBase + mt * 4096 + kt * 1024);
    f32x4 acc0 = f32x4{0.f, 0.f, 0.f, 0.f};
    f32x4 acc1 = f32x4{0.f, 0.f, 0.f, 0.f};
#pragma unroll
    for (int kt = 0; kt < 4; ++kt) {
      acc0 = __builtin_amdgcn_mfma_f32_16x16x32_bf16(WA[0][kt], B[kt], acc0, 0, 0, 0);
      acc1 = __builtin_amdgcn_mfma_f32_16x16x32_bf16(WA[1][kt], B[kt], acc1, 0, 0, 0);
    }
    {
      unsigned q01 = tanh2_acc(acc0[0], acc0[1], f32x2{bcl0[0], bcl0[1]});
      unsigned q23 = tanh2_acc(acc0[2], acc0[3], f32x2{bcl0[2], bcl0[3]});
      *(uint2*)(bufW + wBase0 + mt * 4096) = uint2{q01, q23};
    }
    {
      unsigned q01 = tanh2_acc(acc1[0], acc1[1], f32x2{bcl1[0], bcl1[1]});
      unsigned q23 = tanh2_acc(acc1[2], acc1[3], f32x2{bcl1[2], bcl1[3]});
      *(uint2*)(bufW + wBase1 + mt * 4096) = uint2{q01, q23};
    }
  }
}

__global__ __launch_bounds__(256, 3)
void mlp_kernel(const float* __restrict__ xy, const float* __restrict__ Uin,
                const float* __restrict__ W1, const float* __restrict__ b1,
                const float* __restrict__ b2, const float* __restrict__ b3,
                const float* __restrict__ b4, const float* __restrict__ b5,
                const unsigned short* __restrict__ ws, float* __restrict__ out)
{
  // ping-pong h buffers, FRAGMENT-MAJOR, 64-point tile (mt=0..3):
  //   hbuf[(mt*4+kt)*1024 + lane*16 + e*2] = h[mt*16+(lane&15)][kt*32+(lane>>4)*8+e]
  __shared__ __align__(16) unsigned char hbuf0[16384];
  __shared__ __align__(16) unsigned char hbuf1[16384];
  __shared__ __align__(16) float         w1tab[384];   // C2-prescaled w1x,w1y,b1
  __shared__ __align__(16) float         bctab[384];   // [l*128+n] = b_{l+2}[n]*C2
  __shared__ __align__(16) unsigned short b5tab[2048]; // W5 A-frag image

  const int tid  = threadIdx.x;
  const int lane = tid & 63;
  const int wid  = tid >> 6;   // 0..3 : n-column group of 32
  const int lg   = lane >> 4;  // 0..3
  const int ln   = lane & 15;
  const int o    = tid >> 4;   // layer-1 n-octet 0..15
  const int c0   = tid & 15;   // layer-1 point-within-16

  const float Uval = Uin[0];
  const float b50  = b5[0];
  const float b51  = b5[1];

  // ---- stage LDS tables (layer-1 tables PRE-SCALED by C2) ----
  if (tid < 128) {
    w1tab[tid]       = W1[tid] * C2;
    w1tab[128 + tid] = W1[128 + tid] * C2;
    w1tab[256 + tid] = b1[tid] * C2;
    bctab[tid]       = b2[tid] * C2;
    bctab[128 + tid] = b3[tid] * C2;
    bctab[256 + tid] = b4[tid] * C2;
  }
  ((uint4*)b5tab)[tid] = ((const uint4*)(ws + 49152))[tid];

  // ---- W3,W4 A-fragments: opaque asm loads, pinned for the whole kernel ----
  s16x8 Wa3[2][4], Wa4[2][4];
#pragma unroll
  for (int nb = 0; nb < 2; ++nb)
#pragma unroll
    for (int kt = 0; kt < 4; ++kt) {
      unsigned voff3 = ((unsigned)(((1 * 8 + wid * 2 + nb) * 4 + kt)) << 10) + (unsigned)(lane * 16);
      unsigned voff4 = ((unsigned)(((2 * 8 + wid * 2 + nb) * 4 + kt)) << 10) + (unsigned)(lane * 16);
      asm volatile("global_load_dwordx4 %0, %1, %2"
                   : "=v"(Wa3[nb][kt]) : "v"(voff3), "s"(ws));
      asm volatile("global_load_dwordx4 %0, %1, %2"
                   : "=v"(Wa4[nb][kt]) : "v"(voff4), "s"(ws));
    }
  asm volatile("s_waitcnt vmcnt(0)");
  __builtin_amdgcn_sched_barrier(0);
  __syncthreads();   // tables staged

  // ---- LDS byte bases (all linear, no swizzle) ----
  const unsigned rBase  = (unsigned)(lane * 16);   // + mt*4096 + kt*1024
  const unsigned wBase0 = (unsigned)(wid * 1024 + (lg >> 1) * 256 + ln * 16 + (lg & 1) * 8);
  const unsigned wBase1 = wBase0 + 512;
  const unsigned l1Base = (unsigned)((o >> 2) * 1024 + (o & 3) * 256 + c0 * 16);

  for (int tile = blockIdx.x; tile < NTILE; tile += GRID) {
    const int pbase = tile << 6;

    // ---- stream this tile's W2 fragments (L1/L2-resident) ----
    s16x8 W2f[2][4];
#pragma unroll
    for (int nb = 0; nb < 2; ++nb)
#pragma unroll
      for (int kt = 0; kt < 4; ++kt)
        W2f[nb][kt] = *(const s16x8*)(ws + (((0 * 8 + wid * 2 + nb) * 4 + kt) << 9) + lane * 8);

    // ---- layer 1: h1 = tanh(xy@W1+b1) -> hbuf0 (tables pre-scaled by C2) ----
    {
      const f32x4 wxa = *(const f32x4*)(w1tab + o * 8);
      const f32x4 wxb = *(const f32x4*)(w1tab + o * 8 + 4);
      const f32x4 wya = *(const f32x4*)(w1tab + 128 + o * 8);
      const f32x4 wyb = *(const f32x4*)(w1tab + 128 + o * 8 + 4);
      const f32x4 bba = *(const f32x4*)(w1tab + 256 + o * 8);
      const f32x4 bbb = *(const f32x4*)(w1tab + 256 + o * 8 + 4);
#pragma unroll
      for (int i = 0; i < 4; ++i) {
        int p = i * 16 + c0;
        float2 v = ((const float2*)xy)[pbase + p];
        const f32x2 vx = { v.x, v.x };
        const f32x2 vy = { v.y, v.y };
        unsigned q[4];
#pragma unroll
        for (int t2 = 0; t2 < 2; ++t2) {
          // packed dot: s2 = vx*wx01 + (vy*wy01 + b01)  (2x v_pk_fma_f32)
          f32x2 wx01 = { wxa[2 * t2], wxa[2 * t2 + 1] };
          f32x2 wy01 = { wya[2 * t2], wya[2 * t2 + 1] };
          f32x2 b01  = { bba[2 * t2], bba[2 * t2 + 1] };
          f32x2 s2 = __builtin_elementwise_fma(vx, wx01,
                       __builtin_elementwise_fma(vy, wy01, b01));
          q[t2] = tanh2_pre(s2);
        }
#pragma unroll
        for (int t2 = 0; t2 < 2; ++t2) {
          f32x2 wx01 = { wxb[2 * t2], wxb[2 * t2 + 1] };
          f32x2 wy01 = { wyb[2 * t2], wyb[2 * t2 + 1] };
          f32x2 b01  = { bbb[2 * t2], bbb[2 * t2 + 1] };
          f32x2 s2 = __builtin_elementwise_fma(vx, wx01,
                       __builtin_elementwise_fma(vy, wy01, b01));
          q[2 + t2] = tanh2_pre(s2);
        }
        *(uint4*)(hbuf0 + l1Base + i * 4096) = uint4{q[0], q[1], q[2], q[3]};
      }
    }
    __syncthreads();   // h1 visible (also drains W2f loads)

    // ---- layers 2..4 ----
    layer_fwd(W2f, hbuf0, hbuf1, bctab,       rBase, wBase0, wBase1, wid, lg);
    __syncthreads();
    layer_fwd(Wa3, hbuf1, hbuf0, bctab + 128, rBase, wBase0, wBase1, wid, lg);
    __syncthreads();
    layer_fwd(Wa4, hbuf0, hbuf1, bctab + 256, rBase, wBase0, wBase1, wid, lg);
    __syncthreads();

    // ---- layer 5 + epilogue (reads hbuf1 = L4 out; wave: 16 points, mt=wid) ----
    f32x4 acc5 = f32x4{0.f, 0.f, 0.f, 0.f};
#pragma unroll
    for (int kt = 0; kt < 4; ++kt) {
      s16x8 b5f = *(const s16x8*)(b5tab + kt * 512 + lane * 8);
      s16x8 b   = *(const s16x8*)(hbuf1 + rBase + wid * 4096 + kt * 1024);
      acc5 = __builtin_amdgcn_mfma_f32_16x16x32_bf16(b5f, b, acc5, 0, 0, 0);
    }
    if (lg == 0) {
      int p = pbase + wid * 16 + ln;
      float uh = acc5[0] + b50;
      float vh = acc5[1] + b51;
      float2 v = ((const float2*)xy)[p];
      float Bm = v.x * (1.0f - v.x) * v.y * (1.0f - v.y);
      float psi = sigm_fast(50.0f * (v.x - 0.05f)) * sigm_fast(50.0f * (0.95f - v.x));
      out[p]        = fmaf(Uval * v.y, psi, Bm * uh);
      out[NPTS + p] = Bm * vh;
    }
    // no trailing barrier: next L1 writes hbuf0 (last readers are behind the L4
    // barrier); next L2 writes hbuf1 after the post-L1 barrier, after L5 reads.
  }
}

extern "C" void kernel_launch(void* const* d_in, const int* in_sizes, int n_in,
                              void* d_out, int out_size, void* d_ws, size_t ws_size,
                              hipStream_t stream) {
  const float* xy = (const float*)d_in[0];
  const float* U  = (const float*)d_in[1];
  const float* W1 = (const float*)d_in[2];
  const float* b1 = (const float*)d_in[3];
  const float* W2 = (const float*)d_in[4];
  const float* b2 = (const float*)d_in[5];
  const float* W3 = (const float*)d_in[6];
  const float* b3 = (const float*)d_in[7];
  const float* W4 = (const float*)d_in[8];
  const float* b4 = (const float*)d_in[9];
  const float* W5 = (const float*)d_in[10];
  const float* b5 = (const float*)d_in[11];
  unsigned short* ws = (unsigned short*)d_ws;   // needs ~100 KB
  float* out = (float*)d_out;

  prep_kernel<<<200, 256, 0, stream>>>(W2, W3, W4, W5, ws);
  mlp_kernel<<<GRID, 256, 0, stream>>>(xy, U, W1, b1, b2, b3, b4, b5, ws, out);
}